// Round 1
// baseline (375.098 us; speedup 1.0000x reference)
//
#include <hip/hip_runtime.h>
#include <hip/hip_bf16.h>
#include <math.h>

// ---------------- types ----------------
typedef __bf16 bf16_t;
typedef __bf16 bf16x4 __attribute__((ext_vector_type(4)));
typedef __bf16 bf16x8 __attribute__((ext_vector_type(8)));
typedef float  f32x4  __attribute__((ext_vector_type(4)));

#define T_TOK 4096
#define H_DIM 1024
#define E_NUM 16
#define F_DIM 4096
#define CH_MAX 16   // max token chunks of 256 per expert (covers worst case 4096)

// ---------------- workspace layout (bytes) ----------------
#define WS_E0     0            // int[4096]
#define WS_E1     16384        // int[4096]
#define WS_W0     32768        // float[4096]
#define WS_W1     49152        // float[4096]
#define WS_COUNTS 65536        // int[16]
#define WS_SUMW   65792        // float[16]
#define WS_LIDX   131072       // int[16][4096]
#define WS_LW     393216       // float[16][4096]
#define WS_GPART  655360       // float[16][16][4096]  (4 MB)
#define WS_G      4849664      // float[16][4096]
#define WS_P2     5105664      // float[512][1024]     (2 MB)
// total: 7,202,816 bytes

// ---------------- kernel 1: routing (scores + top2 + softmax) ----------------
__global__ __launch_bounds__(64) void k_route(const float* __restrict__ x,
    const float* __restrict__ Wg, const float* __restrict__ bg,
    int* __restrict__ e0, int* __restrict__ e1,
    float* __restrict__ w0, float* __restrict__ w1)
{
    const int t = blockIdx.x;
    const int lane = threadIdx.x;
    const float* xr = x + (size_t)t * H_DIM;

    float s[E_NUM];
#pragma unroll
    for (int e = 0; e < E_NUM; ++e) s[e] = 0.f;

#pragma unroll
    for (int i = 0; i < 16; ++i) {
        const int h = i * 64 + lane;
        const float xv = xr[h];
        const float4* wr = (const float4*)(Wg + (size_t)h * E_NUM);
        float4 q0 = wr[0], q1 = wr[1], q2 = wr[2], q3 = wr[3];
        s[0] += xv*q0.x;  s[1] += xv*q0.y;  s[2] += xv*q0.z;  s[3] += xv*q0.w;
        s[4] += xv*q1.x;  s[5] += xv*q1.y;  s[6] += xv*q1.z;  s[7] += xv*q1.w;
        s[8] += xv*q2.x;  s[9] += xv*q2.y;  s[10]+= xv*q2.z;  s[11]+= xv*q2.w;
        s[12]+= xv*q3.x;  s[13]+= xv*q3.y;  s[14]+= xv*q3.z;  s[15]+= xv*q3.w;
    }
#pragma unroll
    for (int off = 32; off >= 1; off >>= 1) {
#pragma unroll
        for (int e = 0; e < E_NUM; ++e) s[e] += __shfl_xor(s[e], off);
    }
    if (lane == 0) {
#pragma unroll
        for (int e = 0; e < E_NUM; ++e) s[e] += bg[e];
        float b1v = -3e38f; int i1 = 0;
#pragma unroll
        for (int e = 0; e < E_NUM; ++e) { if (s[e] > b1v) { b1v = s[e]; i1 = e; } }
        float b2v = -3e38f; int i2 = 0;
#pragma unroll
        for (int e = 0; e < E_NUM; ++e) { if (e != i1 && s[e] > b2v) { b2v = s[e]; i2 = e; } }
        const float ex  = expf(b2v - b1v);          // <= 1
        const float inv = 1.f / (1.f + ex);
        e0[t] = i1; e1[t] = i2;
        w0[t] = inv; w1[t] = ex * inv;
    }
}

// ---------------- kernel 2: per-expert token lists (deterministic ballot compaction) ----------------
__global__ __launch_bounds__(64) void k_lists(const int* __restrict__ e0, const int* __restrict__ e1,
    const float* __restrict__ w0, const float* __restrict__ w1,
    int* __restrict__ lidx, float* __restrict__ lw,
    int* __restrict__ counts, float* __restrict__ sumw)
{
    const int e = blockIdx.x;
    const int lane = threadIdx.x;
    int cnt = 0; float sw = 0.f;
    for (int base = 0; base < T_TOK; base += 64) {
        const int t = base + lane;
        const bool m0 = (e0[t] == e);
        const bool m1 = (e1[t] == e);
        const bool m  = m0 | m1;
        const unsigned long long bal = __ballot(m);
        const int pos = cnt + __popcll(bal & ((1ull << lane) - 1ull));
        if (m) {
            const float w = m0 ? w0[t] : w1[t];
            lidx[e * T_TOK + pos] = t;
            lw[e * T_TOK + pos]   = w;
            sw += w;
        }
        cnt += __popcll(bal);
    }
#pragma unroll
    for (int off = 32; off >= 1; off >>= 1) sw += __shfl_xor(sw, off);
    if (lane == 0) { counts[e] = cnt; sumw[e] = sw; }
}

// ---------------- kernel 3: expert GEMM (bf16 MFMA) + fused gelu + weighted token-reduce ----------------
// grid: x = F/64 f-tiles (64), y = chunk (16), z = expert (16); block = 512 (8 waves: 4M x 2N)
// Per block: computes sum_t w[t] * gelu(x[t]@W1[e] + b1)[f-tile] over its 256-token chunk.
__global__ __launch_bounds__(512) void k_expert(const float* __restrict__ x,
    const float* __restrict__ W1, const float* __restrict__ b1,
    const int* __restrict__ lidx, const float* __restrict__ lw,
    const int* __restrict__ counts, float* __restrict__ gpart)
{
    const int ftile = blockIdx.x;   // 0..63
    const int chunk = blockIdx.y;   // 0..15
    const int e     = blockIdx.z;   // 0..15
    const int cnt   = counts[e];
    const int start = chunk * 256;
    if (chunk > 0 && start >= cnt) return;
    int valid = cnt - start;
    if (valid > 256) valid = 256;
    if (valid < 0)   valid = 0;

    __shared__ bf16_t Alds[256][40];   // 32 K + 8 pad (16B-aligned rows, uniform 2-way banks)
    __shared__ bf16_t Blds[64][40];    // W1 tile transposed: [f][k]
    __shared__ int    tok_s[256];
    __shared__ float  w_s[256];
    __shared__ float  b1_s[64];
    __shared__ float  gred[4][64];

    const int tid = threadIdx.x;
    if (tid < 256) {
        const int r = start + tid;
        const bool ok = (tid < valid);
        tok_s[tid] = ok ? lidx[e * T_TOK + r] : 0;
        w_s[tid]   = ok ? lw[e * T_TOK + r]   : 0.f;
    } else if (tid < 320) {
        const int f = tid - 256;
        b1_s[f] = b1[(size_t)e * F_DIM + ftile * 64 + f];
    }
    __syncthreads();

    const int lane = tid & 63;
    const int wid  = tid >> 6;
    const int wm   = wid & 3;        // wave row group (64 tokens)
    const int wn   = wid >> 2;       // wave col group (32 f)
    const int lr   = lane & 15;
    const int lg   = lane >> 4;

    f32x4 acc[4][2];
#pragma unroll
    for (int i = 0; i < 4; ++i)
#pragma unroll
        for (int j = 0; j < 2; ++j)
#pragma unroll
            for (int q = 0; q < 4; ++q) acc[i][j][q] = 0.f;

    const float* W1e = W1 + (size_t)e * H_DIM * F_DIM + (size_t)ftile * 64;

    const int arow0 = tid >> 3;      // 0..63
    const int aquad = tid & 7;       // 0..7  (float4 within 32-float row)
    const int bf    = tid & 63;      // f within tile
    const int bk0   = tid >> 6;      // 0..7

    for (int k0 = 0; k0 < H_DIM; k0 += 32) {
        // stage A: gathered x rows, f32 -> bf16
#pragma unroll
        for (int p = 0; p < 4; ++p) {
            const int row = arow0 + p * 64;
            const float4 v = *(const float4*)(x + (size_t)tok_s[row] * H_DIM + k0 + aquad * 4);
            bf16x4 bv;
            bv[0] = (bf16_t)v.x; bv[1] = (bf16_t)v.y; bv[2] = (bf16_t)v.z; bv[3] = (bf16_t)v.w;
            *(bf16x4*)&Alds[row][aquad * 4] = bv;
        }
        // stage B: W1 tile (coalesced global read, transposed scatter to LDS)
#pragma unroll
        for (int p = 0; p < 4; ++p) {
            const int k = bk0 + p * 8;
            const float v = W1e[(size_t)(k0 + k) * F_DIM + bf];
            Blds[bf][k] = (bf16_t)v;
        }
        __syncthreads();

        bf16x8 afrag[4], bfrag[2];
#pragma unroll
        for (int mf = 0; mf < 4; ++mf)
            afrag[mf] = *(const bf16x8*)&Alds[wm * 64 + mf * 16 + lr][lg * 8];
#pragma unroll
        for (int nf = 0; nf < 2; ++nf)
            bfrag[nf] = *(const bf16x8*)&Blds[wn * 32 + nf * 16 + lr][lg * 8];
#pragma unroll
        for (int mf = 0; mf < 4; ++mf)
#pragma unroll
            for (int nf = 0; nf < 2; ++nf)
                acc[mf][nf] = __builtin_amdgcn_mfma_f32_16x16x32_bf16(afrag[mf], bfrag[nf], acc[mf][nf], 0, 0, 0);
        __syncthreads();
    }

    // epilogue: exact gelu + weighted reduction over token rows
    float gcol[2] = {0.f, 0.f};
#pragma unroll
    for (int nf = 0; nf < 2; ++nf) {
        const float bb = b1_s[wn * 32 + nf * 16 + lr];
#pragma unroll
        for (int mf = 0; mf < 4; ++mf) {
#pragma unroll
            for (int i = 0; i < 4; ++i) {
                const int row = wm * 64 + mf * 16 + lg * 4 + i;  // C/D: col=lane&15, row=(lane>>4)*4+reg
                const float h  = acc[mf][nf][i] + bb;
                const float gl = 0.5f * h * (1.f + erff(h * 0.70710678118654752f));
                gcol[nf] += w_s[row] * gl;
            }
        }
    }
#pragma unroll
    for (int nf = 0; nf < 2; ++nf) {
        gcol[nf] += __shfl_xor(gcol[nf], 16);
        gcol[nf] += __shfl_xor(gcol[nf], 32);
    }
    if (lane < 16) {
#pragma unroll
        for (int nf = 0; nf < 2; ++nf)
            gred[wm][wn * 32 + nf * 16 + lane] = gcol[nf];
    }
    __syncthreads();
    if (tid < 64) {
        const float sum = gred[0][tid] + gred[1][tid] + gred[2][tid] + gred[3][tid];
        gpart[(size_t)(e * CH_MAX + chunk) * F_DIM + ftile * 64 + tid] = sum;
    }
}

// ---------------- kernel 4: reduce chunk partials -> g[e][F] ----------------
__global__ __launch_bounds__(256) void k_redg(const float* __restrict__ gpart,
    const int* __restrict__ counts, float* __restrict__ g)
{
    const int e = blockIdx.y;
    const int f = blockIdx.x * 256 + threadIdx.x;
    const int nch = (counts[e] + 255) >> 8;
    float s = 0.f;
    for (int c = 0; c < nch; ++c)
        s += gpart[(size_t)(e * CH_MAX + c) * F_DIM + f];
    g[(size_t)e * F_DIM + f] = s;
}

// ---------------- kernel 5: W2 GEMV partials ----------------
// grid: x = 32 f-chunks (128 each), y = 16 experts; block 256 (each thread 4 h via float4)
__global__ __launch_bounds__(256) void k_out1(const float* __restrict__ g,
    const float* __restrict__ W2, float* __restrict__ p2)
{
    const int fc = blockIdx.x;
    const int e  = blockIdx.y;
    const int tid = threadIdx.x;
    __shared__ float gs[128];
    if (tid < 128) gs[tid] = g[(size_t)e * F_DIM + fc * 128 + tid];
    __syncthreads();
    const float* W2p = W2 + (size_t)e * F_DIM * H_DIM + (size_t)fc * 128 * H_DIM;
    float ax = 0.f, ay = 0.f, az = 0.f, aw = 0.f;
#pragma unroll 4
    for (int f = 0; f < 128; ++f) {
        const float gv = gs[f];
        const float4 wv = *(const float4*)(W2p + (size_t)f * H_DIM + tid * 4);
        ax += gv * wv.x; ay += gv * wv.y; az += gv * wv.z; aw += gv * wv.w;
    }
    float4 st; st.x = ax; st.y = ay; st.z = az; st.w = aw;
    *(float4*)(p2 + (size_t)(e * 32 + fc) * H_DIM + tid * 4) = st;
}

// ---------------- kernel 6: final reduce + bias + normalize ----------------
// grid: 32 blocks x 256; each block produces 32 h outputs
__global__ __launch_bounds__(256) void k_out2(const float* __restrict__ p2,
    const float* __restrict__ sumw, const float* __restrict__ b2, float* __restrict__ out)
{
    const int tid = threadIdx.x;
    const int hh  = tid & 31;
    const int seg = tid >> 5;     // 0..7
    const int h   = blockIdx.x * 32 + hh;
    float s = 0.f;
    for (int j = 0; j < 64; ++j)
        s += p2[(size_t)(seg * 64 + j) * H_DIM + h];
    __shared__ float red[8][33];
    red[seg][hh] = s;
    __syncthreads();
    if (tid < 32) {
        const int h2 = blockIdx.x * 32 + tid;
        float tot = 0.f;
#pragma unroll
        for (int q = 0; q < 8; ++q) tot += red[q][tid];
        float tw = 0.f, bias = 0.f;
#pragma unroll
        for (int e = 0; e < E_NUM; ++e) { tw += sumw[e]; bias += sumw[e] * b2[e * H_DIM + h2]; }
        out[h2] = (tot + bias) / tw;
    }
}

// ---------------- launch ----------------
extern "C" void kernel_launch(void* const* d_in, const int* in_sizes, int n_in,
                              void* d_out, int out_size, void* d_ws, size_t ws_size,
                              hipStream_t stream) {
    const float* x  = (const float*)d_in[0];
    const float* Wg = (const float*)d_in[1];
    const float* bg = (const float*)d_in[2];
    const float* W1 = (const float*)d_in[3];
    const float* b1 = (const float*)d_in[4];
    const float* W2 = (const float*)d_in[5];
    const float* b2 = (const float*)d_in[6];
    float* out = (float*)d_out;

    char* ws = (char*)d_ws;
    int*   e0     = (int*)(ws + WS_E0);
    int*   e1     = (int*)(ws + WS_E1);
    float* w0     = (float*)(ws + WS_W0);
    float* w1     = (float*)(ws + WS_W1);
    int*   counts = (int*)(ws + WS_COUNTS);
    float* sumw   = (float*)(ws + WS_SUMW);
    int*   lidx   = (int*)(ws + WS_LIDX);
    float* lw     = (float*)(ws + WS_LW);
    float* gpart  = (float*)(ws + WS_GPART);
    float* g      = (float*)(ws + WS_G);
    float* p2     = (float*)(ws + WS_P2);

    k_route<<<T_TOK, 64, 0, stream>>>(x, Wg, bg, e0, e1, w0, w1);
    k_lists<<<E_NUM, 64, 0, stream>>>(e0, e1, w0, w1, lidx, lw, counts, sumw);
    k_expert<<<dim3(F_DIM / 64, CH_MAX, E_NUM), 512, 0, stream>>>(x, W1, b1, lidx, lw, counts, gpart);
    k_redg<<<dim3(F_DIM / 256, E_NUM), 256, 0, stream>>>(gpart, counts, g);
    k_out1<<<dim3(32, E_NUM), 256, 0, stream>>>(g, W2, p2);
    k_out2<<<32, 256, 0, stream>>>(p2, sumw, b2, out);
}